// Round 1
// 243.748 us; speedup vs baseline: 1.0574x; 1.0574x over previous
//
#include <hip/hip_runtime.h>
#include <hip/hip_bf16.h>
#include <math.h>

// Problem constants
#define Bsz   256
#define INDIM 2048
#define Dd    128
#define Kq    65536
#define NH    32
#define S1n   16
#define S2n   16
#define ROWLEN (1 + Kq + S1n + S2n)   // 65569
#define CAP   2048                     // finalize candidate cap
#define CAPL  6144                     // topcand LDS collection cap
#define NCHUNK 8                       // split-K chunks of 256 for encoder GEMM
#define CK    256                      // K per chunk

typedef __attribute__((ext_vector_type(8))) short short8;
typedef __attribute__((ext_vector_type(4))) float f32x4;
typedef float float4a __attribute__((ext_vector_type(4), aligned(4)));
union U16x8 { uint4 u4; short8 s8; };

static __device__ inline unsigned short bf16rne(float f) {
    unsigned u = __float_as_uint(f);
    unsigned r = (u + 0x7FFFu + ((u >> 16) & 1u)) >> 16;
    return (unsigned short)r;
}
static __device__ inline unsigned fkey(float f) {   // monotone uint key
    unsigned u = __float_as_uint(f);
    return (u & 0x80000000u) ? ~u : (u | 0x80000000u);
}
static __device__ inline float funkey(unsigned key) {
    unsigned u = (key & 0x80000000u) ? (key & 0x7FFFFFFFu) : ~key;
    return __uint_as_float(u);
}

// ---------------- Kernel A0: form Wk_new = 0.999*Wk + 0.001*Wq (fp32, matches ref rounding) ----
// out_k only feeds logits_pos (never the top-K ranking), so fp32 weight rounding
// — which is exactly what the JAX reference does — is safe.
__global__ __launch_bounds__(256) void moco_a0(const float* __restrict__ Wq,
                                               const float* __restrict__ Wk,
                                               float* __restrict__ wknew) {
    int i = blockIdx.x * 256 + threadIdx.x;       // float4 index, 65536 total
    float4 wq = ((const float4*)Wq)[i];
    float4 wk = ((const float4*)Wk)[i];
    float4 wn;
    wn.x = 0.999f * wk.x + 0.001f * wq.x;
    wn.y = 0.999f * wk.y + 0.001f * wq.y;
    wn.z = 0.999f * wk.z + 0.001f * wq.z;
    wn.w = 0.999f * wk.w + 0.001f * wq.w;
    ((float4*)wknew)[i] = wn;
}

// ---------------- Kernel A1: fp64 split-K encoder GEMM (latency-optimized) ----
// Was 59 us at 17% VALUBusy / 15% occupancy: latency-bound on per-iter L2 loads
// with only 8 waves/CU. Now: 2 cols/thread -> grid (8,128) = 16 waves/CU,
// unroll 16 for deep load pipelining, and the k-path uses precombined Wk_new
// (2 FMAs/iter instead of 8). q-path f64 chain is bitwise-identical to before.
__global__ __launch_bounds__(256) void moco_a1(const float* __restrict__ q,
                                               const float* __restrict__ k,
                                               const float* __restrict__ Wq,
                                               const float* __restrict__ wknew,
                                               double* __restrict__ partq,
                                               float* __restrict__ partk) {
    int kc    = blockIdx.x;        // 0..NCHUNK-1
    int grp   = blockIdx.y;        // 0..127, 4 rows each
    int vrow0 = grp * 4;
    bool isK  = (vrow0 >= Bsz);
    const float* inp = isK ? k : q;
    const float* W   = isK ? wknew : Wq;
    int row0 = isK ? (vrow0 - Bsz) : vrow0;
    int i0 = kc * CK;

    __shared__ float s_in[4 * CK];
    #pragma unroll
    for (int it = 0; it < 4; ++it) {
        int idx = threadIdx.x + it * 256;
        int rr = idx >> 8, ii = idx & (CK - 1);
        s_in[idx] = inp[(size_t)(row0 + rr) * INDIM + i0 + ii];
    }
    __syncthreads();

    int ct = threadIdx.x & 63;     // one wave == one row -> srow reads broadcast
    int rt = threadIdx.x >> 6;
    int d0 = ct * 2;
    const float* baseW = W + (size_t)i0 * Dd + d0;
    const float* srow = &s_in[rt * CK];

    double acc0 = 0, acc1 = 0;
    #pragma unroll 16
    for (int i = 0; i < CK; ++i) {
        float2 w = *(const float2*)(baseW + (size_t)i * Dd);
        double a = (double)srow[i];
        acc0 += a * (double)w.x;
        acc1 += a * (double)w.y;
    }

    int prow = row0 + rt;
    if (isK) {
        // fp32 partials: out_k only affects logits_pos (error ~1e-7 << tol)
        float2 r; r.x = (float)acc0; r.y = (float)acc1;
        *(float2*)(partk + ((size_t)kc * 256 + prow) * Dd + d0) = r;
    } else {
        double2 r; r.x = acc0; r.y = acc1;
        *(double2*)(partq + ((size_t)kc * 256 + prow) * Dd + d0) = r;
    }
}

// ---------------- Kernel A2: combine, normalize (f64), pos logit, labels, bf16 out_q ----
__global__ __launch_bounds__(128) void moco_a2(const double* __restrict__ partq,
                                               const float* __restrict__ partk,
                                               double* __restrict__ outq64,
                                               unsigned short* __restrict__ outq16,
                                               unsigned* __restrict__ rowmaxkey,
                                               float* __restrict__ out) {
    int b = blockIdx.x, d = threadIdx.x;
    if (b < 2) rowmaxkey[b * 128 + d] = 0;   // init for gemmB's atomicMax
    double sq = 0, sk = 0;
    #pragma unroll
    for (int kc = 0; kc < NCHUNK; ++kc) {
        sq += partq[((size_t)kc * 256 + b) * Dd + d];
        sk += (double)partk[((size_t)kc * 256 + b) * Dd + d];
    }
    __shared__ double red[128];
    red[d] = sq * sq; __syncthreads();
    for (int s = 64; s > 0; s >>= 1) { if (d < s) red[d] += red[d + s]; __syncthreads(); }
    double nq = sqrt(red[0]); __syncthreads();
    red[d] = sk * sk; __syncthreads();
    for (int s = 64; s > 0; s >>= 1) { if (d < s) red[d] += red[d + s]; __syncthreads(); }
    double nk = sqrt(red[0]); __syncthreads();

    double oq = sq / fmax(nq, 1e-12);
    double ok = sk / fmax(nk, 1e-12);
    outq64[(size_t)b * Dd + d] = oq;
    outq16[(size_t)b * Dd + d] = bf16rne((float)oq);

    red[d] = oq * ok; __syncthreads();
    for (int s = 64; s > 0; s >>= 1) { if (d < s) red[d] += red[d + s]; __syncthreads(); }
    if (d == 0) {
        out[(size_t)b * ROWLEN] = (float)(red[0] / 0.07);
        ((int*)out)[(size_t)Bsz * ROWLEN + b] = 0;   // labels
    }
}

// ---------------- Kernel B: bf16 MFMA GEMM + per-row max -> out[:,1:1+K] -------
#define GB_BN 64
__global__ __launch_bounds__(256) void moco_gemmB(const unsigned short* __restrict__ outq16,
                                                  const float* __restrict__ Q,
                                                  unsigned* __restrict__ rowmaxkey,
                                                  float* __restrict__ out) {
    int bn0 = blockIdx.x * GB_BN;
    int tid = threadIdx.x;
    int w = tid >> 6, lane = tid & 63;
    int quad = lane >> 4, l16 = lane & 15;

    __shared__ unsigned short q_lds[64 * 136];   // stride 136 bf16
    __shared__ unsigned s_rmax[256];
    s_rmax[tid] = 0;

    // stage Q tile: 64 rows x 128 k, convert fp32->bf16 (RNE)
    #pragma unroll
    for (int it = 0; it < 4; ++it) {
        int chunk = tid + it * 256;          // 0..1023
        int row = chunk >> 4, kb = chunk & 15;
        const float4* g = (const float4*)(Q + (size_t)(bn0 + row) * Dd + kb * 8);
        float4 f0 = g[0], f1 = g[1];
        uint4 pk;
        pk.x = ((unsigned)bf16rne(f0.y) << 16) | bf16rne(f0.x);
        pk.y = ((unsigned)bf16rne(f0.w) << 16) | bf16rne(f0.z);
        pk.z = ((unsigned)bf16rne(f1.y) << 16) | bf16rne(f1.x);
        pk.w = ((unsigned)bf16rne(f1.w) << 16) | bf16rne(f1.z);
        *(uint4*)&q_lds[row * 136 + kb * 8] = pk;
    }

    // A fragments from global bf16 (L2-hot 64 KB)
    short8 afr[4][4];
    #pragma unroll
    for (int i = 0; i < 4; ++i)
        #pragma unroll
        for (int kc = 0; kc < 4; ++kc) {
            U16x8 u;
            u.u4 = *(const uint4*)(outq16 + (size_t)(w * 64 + i * 16 + l16) * Dd + kc * 32 + quad * 8);
            afr[i][kc] = u.s8;
        }
    __syncthreads();

    f32x4 acc[4][4];
    #pragma unroll
    for (int i = 0; i < 4; ++i)
        #pragma unroll
        for (int j = 0; j < 4; ++j)
            acc[i][j] = (f32x4){0.f, 0.f, 0.f, 0.f};

    #pragma unroll
    for (int kc = 0; kc < 4; ++kc) {
        short8 bfr[4];
        #pragma unroll
        for (int j = 0; j < 4; ++j)
            bfr[j] = *(const short8*)&q_lds[(j * 16 + l16) * 136 + kc * 32 + quad * 8];
        #pragma unroll
        for (int i = 0; i < 4; ++i)
            #pragma unroll
            for (int j = 0; j < 4; ++j)
                acc[i][j] = __builtin_amdgcn_mfma_f32_16x16x32_bf16(afr[i][kc], bfr[j], acc[i][j], 0, 0, 0);
    }

    const float invT = (float)(1.0 / 0.07);
    #pragma unroll
    for (int i = 0; i < 4; ++i) {
        int rbase = w * 64 + i * 16 + quad * 4;
        #pragma unroll
        for (int reg = 0; reg < 4; ++reg) {
            size_t ro = (size_t)(rbase + reg) * ROWLEN + 1 + bn0;
            float v0 = acc[i][0][reg] * invT;
            float v1 = acc[i][1][reg] * invT;
            float v2 = acc[i][2][reg] * invT;
            float v3 = acc[i][3][reg] * invT;
            out[ro + l16]      = v0;
            out[ro + 16 + l16] = v1;
            out[ro + 32 + l16] = v2;
            out[ro + 48 + l16] = v3;
            float m = fmaxf(fmaxf(v0, v1), fmaxf(v2, v3));
            atomicMax(&s_rmax[rbase + reg], fkey(m));
        }
    }
    __syncthreads();
    // conditional global max: monotone, so a stale read only adds one atomic
    unsigned cur = rowmaxkey[tid];
    unsigned mine = s_rmax[tid];
    if (mine > cur) atomicMax(&rowmaxkey[tid], mine);
}

// ---------------- Kernel C: single-pass window collection + fine LDS prune ----
// Stage 1: collect all values >= vmax - W into LDS (cnt ~ 300).
// Stage 2: 128-bin fine histogram over [vmax-W, vmax]; keep values above the
// rank-NH bin minus a 0.25-logit-unit margin (covers bf16-vs-f64 reorder,
// measured error 0.031; margin validated by R3/R4/R5 passes). Delivers
// n ~ 33-60 to finalize.
__global__ __launch_bounds__(512) void moco_topcand(const float* __restrict__ out,
                                                    const unsigned* __restrict__ rowmaxkey,
                                                    int* __restrict__ cand,
                                                    int* __restrict__ ccnt) {
    int row = blockIdx.x;
    int t = threadIdx.x;
    const float* p = out + (size_t)row * ROWLEN + 1;
    __shared__ float lv[CAPL];
    __shared__ int   li[CAPL];
    __shared__ unsigned hist[128];
    __shared__ int s_cnt, s_thr;

    float vmax = funkey(rowmaxkey[row]);
    float W = 2.0f;
    int cnt = 0;
    const float4a* p4 = (const float4a*)p;

    for (int attempt = 0; attempt < 5; ++attempt) {
        if (t == 0) s_cnt = 0;
        __syncthreads();
        float thresh = vmax - W;
        #pragma unroll 8
        for (int it = 0; it < 32; ++it) {
            int vi = t + it * 512;              // < 16384
            float4a v = p4[vi];
            #pragma unroll
            for (int e = 0; e < 4; ++e) {
                float f = v[e];
                if (f >= thresh) {
                    int pos = atomicAdd(&s_cnt, 1);
                    if (pos < CAPL) { lv[pos] = f; li[pos] = vi * 4 + e; }
                }
            }
        }
        __syncthreads();
        cnt = s_cnt;
        if (cnt >= NH && cnt <= CAPL) break;
        W = (cnt > CAPL) ? W * 0.5f : W * 2.0f;
        __syncthreads();
    }
    if (cnt > CAPL) cnt = CAPL;   // pathological safety

    // ---- stage 2: fine prune (always) ----
    if (t < 128) hist[t] = 0;
    __syncthreads();
    float lo = vmax - W;
    float scale = 128.0f / W;
    for (int c = t; c < cnt; c += 512) {
        int b = (int)((lv[c] - lo) * scale);
        b = b < 0 ? 0 : (b > 127 ? 127 : b);
        atomicAdd(&hist[b], 1u);
    }
    __syncthreads();
    if (t == 0) {
        unsigned cum = 0; int b = 127;
        for (; b > 0; --b) { cum += hist[b]; if (cum >= NH) break; }
        int mb = (int)(0.25f * scale) + 1;     // 0.25 logit-unit safety margin
        b -= mb; if (b < 0) b = 0;
        long total = 0;
        for (int x = 127; x >= b; --x) total += hist[x];
        while (total > CAP && b < 127) { total -= hist[b]; ++b; }
        s_thr = b;
        s_cnt = 0;
    }
    __syncthreads();
    float thresh2 = lo + (float)s_thr * (W / 128.0f);
    for (int c = t; c < cnt; c += 512) {
        if (lv[c] >= thresh2) {
            int pos = atomicAdd(&s_cnt, 1);
            if (pos < CAP) cand[(size_t)row * CAP + pos] = li[c];
        }
    }
    __syncthreads();
    if (t == 0) ccnt[row] = (s_cnt < CAP) ? s_cnt : CAP;
}

// ---------------- Kernel D: fp64 re-rank + mixed-negative logits (R3-verbatim) ----
__global__ __launch_bounds__(256) void moco_finalize(const double* __restrict__ outq64,
                                                     const float* __restrict__ Qm,
                                                     const int* __restrict__ cand,
                                                     const int* __restrict__ ccnt,
                                                     const float* __restrict__ alpha,
                                                     const float* __restrict__ beta,
                                                     const int* __restrict__ i1a,
                                                     const int* __restrict__ i1b,
                                                     const int* __restrict__ i2,
                                                     float* __restrict__ out) {
    int row = blockIdx.x;
    __shared__ double oq[Dd];
    __shared__ double dval[CAP];
    __shared__ int didx[CAP];
    __shared__ int hard[NH];

    for (int i = threadIdx.x; i < Dd; i += 256) oq[i] = outq64[(size_t)row * Dd + i];
    __syncthreads();

    int n = ccnt[row]; if (n > CAP) n = CAP;
    for (int c = threadIdx.x; c < n; c += 256) {
        int idx = cand[(size_t)row * CAP + c];
        const float* qr = Qm + (size_t)idx * Dd;
        double dot = 0;
        #pragma unroll 4
        for (int i = 0; i < Dd; ++i) dot += oq[i] * (double)qr[i];
        dval[c] = dot / 0.07;
        didx[c] = idx;
    }
    __syncthreads();

    // exact rank (ties -> lower index first, matching lax.top_k)
    for (int c = threadIdx.x; c < n; c += 256) {
        double v = dval[c]; int id = didx[c];
        int r = 0;
        for (int j = 0; j < n; ++j) {
            double vj = dval[j];
            r += (vj > v) || (vj == v && didx[j] < id);
        }
        if (r < NH) hard[r] = id;
    }
    __syncthreads();

    int t = threadIdx.x;
    if (t < S1n) {
        double a = (double)alpha[(size_t)row * S1n + t];
        int g1 = hard[i1a[(size_t)row * S1n + t]];
        int g2 = hard[i1b[(size_t)row * S1n + t]];
        const float* q1 = Qm + (size_t)g1 * Dd;
        const float* q2 = Qm + (size_t)g2 * Dd;
        double nn = 0, qd = 0;
        #pragma unroll 4
        for (int i = 0; i < Dd; ++i) {
            double m = a * (double)q1[i] + (1.0 - a) * (double)q2[i];
            nn += m * m; qd += oq[i] * m;
        }
        double logit = qd / fmax(sqrt(nn), 1e-12) / 0.07;
        out[(size_t)row * ROWLEN + 1 + Kq + t] = (float)logit;
    } else if (t < S1n + S2n) {
        int s = t - S1n;
        double bb = (double)beta[(size_t)row * S2n + s] * 0.5;
        int g = hard[i2[(size_t)row * S2n + s]];
        const float* qg = Qm + (size_t)g * Dd;
        double nn = 0, qd = 0;
        #pragma unroll 4
        for (int i = 0; i < Dd; ++i) {
            double m = bb * oq[i] + (1.0 - bb) * (double)qg[i];
            nn += m * m; qd += oq[i] * m;
        }
        double logit = qd / fmax(sqrt(nn), 1e-12) / 0.07;
        out[(size_t)row * ROWLEN + 1 + Kq + S1n + s] = (float)logit;
    }
}

extern "C" void kernel_launch(void* const* d_in, const int* in_sizes, int n_in,
                              void* d_out, int out_size, void* d_ws, size_t ws_size,
                              hipStream_t stream) {
    const float* q     = (const float*)d_in[0];
    const float* k     = (const float*)d_in[1];
    const float* Wq    = (const float*)d_in[2];
    const float* Wk    = (const float*)d_in[3];
    const float* queue = (const float*)d_in[4];
    const float* alpha = (const float*)d_in[5];
    const float* beta  = (const float*)d_in[6];
    const int*   i1a   = (const int*)d_in[7];
    const int*   i1b   = (const int*)d_in[8];
    const int*   i2    = (const int*)d_in[9];
    float* out = (float*)d_out;

    // workspace layout (total 4.31 MB <= previous 4.52 MB):
    //   partq (f64, 2 MB) + partk (f32, 1 MB), both dead after a2
    //   cand (2 MB) aliases partq, born in topcand
    char* ws = (char*)d_ws;
    double* partq  = (double*)(ws);                        // 8*256*128*8 = 2,097,152
    float*  partk  = (float*)(ws + 2097152);               // 8*256*128*4 = 1,048,576
    int*    cand   = (int*)(ws);                           // 256*2048*4  = 2,097,152 (alias partq)
    double* outq64 = (double*)(ws + 3145728);              // 262,144
    unsigned short* outq16 = (unsigned short*)(ws + 3145728 + 262144); // 65,536
    int*    ccnt   = (int*)(ws + 3145728 + 262144 + 65536);            // 1,024
    unsigned* rowmaxkey = (unsigned*)(ws + 3145728 + 262144 + 65536 + 1024); // 1,024
    float* wknew   = (float*)(ws + 3145728 + 262144 + 65536 + 1024 + 1024);  // 1,048,576

    moco_a0<<<dim3(256), 256, 0, stream>>>(Wq, Wk, wknew);
    moco_a1<<<dim3(NCHUNK, 128), 256, 0, stream>>>(q, k, Wq, wknew, partq, partk);
    moco_a2<<<dim3(Bsz), 128, 0, stream>>>(partq, partk, outq64, outq16, rowmaxkey, out);
    moco_gemmB<<<dim3(Kq / GB_BN), 256, 0, stream>>>(outq16, queue, rowmaxkey, out);
    moco_topcand<<<dim3(Bsz), 512, 0, stream>>>(out, rowmaxkey, cand, ccnt);
    moco_finalize<<<dim3(Bsz), 256, 0, stream>>>(outq64, queue, cand, ccnt,
                                                 alpha, beta, i1a, i1b, i2, out);
}

// Round 2
// 233.182 us; speedup vs baseline: 1.1053x; 1.0453x over previous
//
#include <hip/hip_runtime.h>
#include <hip/hip_bf16.h>
#include <math.h>

// Problem constants
#define Bsz   256
#define INDIM 2048
#define Dd    128
#define Kq    65536
#define NH    32
#define S1n   16
#define S2n   16
#define ROWLEN (1 + Kq + S1n + S2n)   // 65569
#define CAP   2048                     // finalize candidate cap
#define CAPL  6144                     // topcand LDS collection cap
#define NCHUNK 8                       // split-K chunks of 256 for encoder GEMM
#define CK    256                      // K per chunk
#define GBLK  512                      // gemmB grid (2 tiles of 64 cols each)

typedef __attribute__((ext_vector_type(8))) short short8;
typedef __attribute__((ext_vector_type(4))) float f32x4;
typedef float float4a __attribute__((ext_vector_type(4), aligned(4)));
union U16x8 { uint4 u4; short8 s8; };

static __device__ inline unsigned short bf16rne(float f) {
    unsigned u = __float_as_uint(f);
    unsigned r = (u + 0x7FFFu + ((u >> 16) & 1u)) >> 16;
    return (unsigned short)r;
}
static __device__ inline unsigned fkey(float f) {   // monotone uint key
    unsigned u = __float_as_uint(f);
    return (u & 0x80000000u) ? ~u : (u | 0x80000000u);
}
static __device__ inline float funkey(unsigned key) {
    unsigned u = (key & 0x80000000u) ? (key & 0x7FFFFFFFu) : ~key;
    return __uint_as_float(u);
}

// ---------------- Kernel A0: form Wk_new = 0.999*Wk + 0.001*Wq (fp32, matches ref rounding) ----
__global__ __launch_bounds__(256) void moco_a0(const float* __restrict__ Wq,
                                               const float* __restrict__ Wk,
                                               float* __restrict__ wknew) {
    int i = blockIdx.x * 256 + threadIdx.x;       // float4 index, 65536 total
    float4 wq = ((const float4*)Wq)[i];
    float4 wk = ((const float4*)Wk)[i];
    float4 wn;
    wn.x = 0.999f * wk.x + 0.001f * wq.x;
    wn.y = 0.999f * wk.y + 0.001f * wq.y;
    wn.z = 0.999f * wk.z + 0.001f * wq.z;
    wn.w = 0.999f * wk.w + 0.001f * wq.w;
    ((float4*)wknew)[i] = wn;
}

// ---------------- Kernel A1: fp64 split-K encoder GEMM (latency-optimized) ----
__global__ __launch_bounds__(256) void moco_a1(const float* __restrict__ q,
                                               const float* __restrict__ k,
                                               const float* __restrict__ Wq,
                                               const float* __restrict__ wknew,
                                               double* __restrict__ partq,
                                               float* __restrict__ partk) {
    int kc    = blockIdx.x;        // 0..NCHUNK-1
    int grp   = blockIdx.y;        // 0..127, 4 rows each
    int vrow0 = grp * 4;
    bool isK  = (vrow0 >= Bsz);
    const float* inp = isK ? k : q;
    const float* W   = isK ? wknew : Wq;
    int row0 = isK ? (vrow0 - Bsz) : vrow0;
    int i0 = kc * CK;

    __shared__ float s_in[4 * CK];
    #pragma unroll
    for (int it = 0; it < 4; ++it) {
        int idx = threadIdx.x + it * 256;
        int rr = idx >> 8, ii = idx & (CK - 1);
        s_in[idx] = inp[(size_t)(row0 + rr) * INDIM + i0 + ii];
    }
    __syncthreads();

    int ct = threadIdx.x & 63;     // one wave == one row -> srow reads broadcast
    int rt = threadIdx.x >> 6;
    int d0 = ct * 2;
    const float* baseW = W + (size_t)i0 * Dd + d0;
    const float* srow = &s_in[rt * CK];

    double acc0 = 0, acc1 = 0;
    #pragma unroll 16
    for (int i = 0; i < CK; ++i) {
        float2 w = *(const float2*)(baseW + (size_t)i * Dd);
        double a = (double)srow[i];
        acc0 += a * (double)w.x;
        acc1 += a * (double)w.y;
    }

    int prow = row0 + rt;
    if (isK) {
        float2 r; r.x = (float)acc0; r.y = (float)acc1;
        *(float2*)(partk + ((size_t)kc * 256 + prow) * Dd + d0) = r;
    } else {
        double2 r; r.x = acc0; r.y = acc1;
        *(double2*)(partq + ((size_t)kc * 256 + prow) * Dd + d0) = r;
    }
}

// ---------------- Kernel A2: combine, normalize (f64), pos logit, labels, bf16 out_q ----
__global__ __launch_bounds__(128) void moco_a2(const double* __restrict__ partq,
                                               const float* __restrict__ partk,
                                               double* __restrict__ outq64,
                                               unsigned short* __restrict__ outq16,
                                               float* __restrict__ out) {
    int b = blockIdx.x, d = threadIdx.x;
    double sq = 0, sk = 0;
    #pragma unroll
    for (int kc = 0; kc < NCHUNK; ++kc) {
        sq += partq[((size_t)kc * 256 + b) * Dd + d];
        sk += (double)partk[((size_t)kc * 256 + b) * Dd + d];
    }
    __shared__ double red[128];
    red[d] = sq * sq; __syncthreads();
    for (int s = 64; s > 0; s >>= 1) { if (d < s) red[d] += red[d + s]; __syncthreads(); }
    double nq = sqrt(red[0]); __syncthreads();
    red[d] = sk * sk; __syncthreads();
    for (int s = 64; s > 0; s >>= 1) { if (d < s) red[d] += red[d + s]; __syncthreads(); }
    double nk = sqrt(red[0]); __syncthreads();

    double oq = sq / fmax(nq, 1e-12);
    double ok = sk / fmax(nk, 1e-12);
    outq64[(size_t)b * Dd + d] = oq;
    outq16[(size_t)b * Dd + d] = bf16rne((float)oq);

    red[d] = oq * ok; __syncthreads();
    for (int s = 64; s > 0; s >>= 1) { if (d < s) red[d] += red[d + s]; __syncthreads(); }
    if (d == 0) {
        out[(size_t)b * ROWLEN] = (float)(red[0] / 0.07);
        ((int*)out)[(size_t)Bsz * ROWLEN + b] = 0;   // labels
    }
}

// ---------------- Kernel B: bf16 MFMA GEMM + per-row max -> out[:,1:1+K] -------
// 2 adjacent 64-col tiles per block (grid 512). A-fragments loaded once.
// Tile-1 queue loads are issued into registers right after the first sync so
// HBM latency hides under tile-0 MFMA + stores. Row maxima: LDS reduce, then
// ONE coalesced 1KB store per block (no device-scope atomics -> no TCC
// same-line serialization across 512 blocks).
#define GB_BN 64
__global__ __launch_bounds__(256) void moco_gemmB(const unsigned short* __restrict__ outq16,
                                                  const float* __restrict__ Q,
                                                  unsigned* __restrict__ rmaxpart,
                                                  float* __restrict__ out) {
    int tid = threadIdx.x;
    int w = tid >> 6, lane = tid & 63;
    int quad = lane >> 4, l16 = lane & 15;
    int bn_base = blockIdx.x * (2 * GB_BN);

    __shared__ unsigned short q_lds[64 * 136];   // stride 136 bf16
    __shared__ unsigned s_rmax[256];
    s_rmax[tid] = 0;

    // A fragments from global bf16 (L2-hot 64 KB), reused across both tiles
    short8 afr[4][4];
    #pragma unroll
    for (int i = 0; i < 4; ++i)
        #pragma unroll
        for (int kc = 0; kc < 4; ++kc) {
            U16x8 u;
            u.u4 = *(const uint4*)(outq16 + (size_t)(w * 64 + i * 16 + l16) * Dd + kc * 32 + quad * 8);
            afr[i][kc] = u.s8;
        }

    // prefetch tile 0 queue rows into registers
    int r0 = tid >> 4, kb = tid & 15;            // 16 rows x 16 col-chunks
    float4 pre[8];
    {
        const float* qb = Q + (size_t)bn_base * Dd + (size_t)kb * 8;
        #pragma unroll
        for (int it = 0; it < 4; ++it) {
            const float4* g = (const float4*)(qb + (size_t)(r0 + it * 16) * Dd);
            pre[2 * it]     = g[0];
            pre[2 * it + 1] = g[1];
        }
    }

    const float invT = (float)(1.0 / 0.07);

    #pragma unroll
    for (int tt = 0; tt < 2; ++tt) {
        int bn0 = bn_base + tt * GB_BN;

        // convert prefetched regs -> LDS (fp32 -> bf16 RNE)
        #pragma unroll
        for (int it = 0; it < 4; ++it) {
            float4 f0 = pre[2 * it], f1 = pre[2 * it + 1];
            uint4 pk;
            pk.x = ((unsigned)bf16rne(f0.y) << 16) | bf16rne(f0.x);
            pk.y = ((unsigned)bf16rne(f0.w) << 16) | bf16rne(f0.z);
            pk.z = ((unsigned)bf16rne(f1.y) << 16) | bf16rne(f1.x);
            pk.w = ((unsigned)bf16rne(f1.w) << 16) | bf16rne(f1.z);
            *(uint4*)&q_lds[(r0 + it * 16) * 136 + kb * 8] = pk;
        }
        __syncthreads();

        // issue tile-1 loads now; they complete under tile-0 MFMA + stores
        if (tt == 0) {
            const float* qb2 = Q + (size_t)(bn_base + GB_BN) * Dd + (size_t)kb * 8;
            #pragma unroll
            for (int it = 0; it < 4; ++it) {
                const float4* g = (const float4*)(qb2 + (size_t)(r0 + it * 16) * Dd);
                pre[2 * it]     = g[0];
                pre[2 * it + 1] = g[1];
            }
        }

        f32x4 acc[4][4];
        #pragma unroll
        for (int i = 0; i < 4; ++i)
            #pragma unroll
            for (int j = 0; j < 4; ++j)
                acc[i][j] = (f32x4){0.f, 0.f, 0.f, 0.f};

        #pragma unroll
        for (int kc = 0; kc < 4; ++kc) {
            short8 bfr[4];
            #pragma unroll
            for (int j = 0; j < 4; ++j)
                bfr[j] = *(const short8*)&q_lds[(j * 16 + l16) * 136 + kc * 32 + quad * 8];
            #pragma unroll
            for (int i = 0; i < 4; ++i)
                #pragma unroll
                for (int j = 0; j < 4; ++j)
                    acc[i][j] = __builtin_amdgcn_mfma_f32_16x16x32_bf16(afr[i][kc], bfr[j], acc[i][j], 0, 0, 0);
        }

        #pragma unroll
        for (int i = 0; i < 4; ++i) {
            int rbase = w * 64 + i * 16 + quad * 4;
            #pragma unroll
            for (int reg = 0; reg < 4; ++reg) {
                size_t ro = (size_t)(rbase + reg) * ROWLEN + 1 + bn0;
                float v0 = acc[i][0][reg] * invT;
                float v1 = acc[i][1][reg] * invT;
                float v2 = acc[i][2][reg] * invT;
                float v3 = acc[i][3][reg] * invT;
                out[ro + l16]      = v0;
                out[ro + 16 + l16] = v1;
                out[ro + 32 + l16] = v2;
                out[ro + 48 + l16] = v3;
                float m = fmaxf(fmaxf(v0, v1), fmaxf(v2, v3));
                atomicMax(&s_rmax[rbase + reg], fkey(m));
            }
        }
        __syncthreads();   // q_lds + s_rmax complete before next tile / final store
    }

    // one coalesced store of this block's 256 per-row maxima
    rmaxpart[(size_t)blockIdx.x * 256 + tid] = s_rmax[tid];
}

// ---------------- Kernel C: row-max reduce + window collection + fine LDS prune ----
__global__ __launch_bounds__(512) void moco_topcand(const float* __restrict__ out,
                                                    const unsigned* __restrict__ rmaxpart,
                                                    int* __restrict__ cand,
                                                    int* __restrict__ ccnt) {
    int row = blockIdx.x;
    int t = threadIdx.x;
    const float* p = out + (size_t)row * ROWLEN + 1;
    __shared__ float lv[CAPL];
    __shared__ int   li[CAPL];
    __shared__ unsigned hist[128];
    __shared__ unsigned s_mk[512];
    __shared__ int s_cnt, s_thr;

    // exact row max from 512 per-block maxima
    s_mk[t] = rmaxpart[(size_t)t * 256 + row];
    __syncthreads();
    for (int s = 256; s > 0; s >>= 1) {
        if (t < s) { unsigned a = s_mk[t], b = s_mk[t + s]; s_mk[t] = a > b ? a : b; }
        __syncthreads();
    }
    float vmax = funkey(s_mk[0]);

    float W = 2.0f;
    int cnt = 0;
    const float4a* p4 = (const float4a*)p;

    for (int attempt = 0; attempt < 5; ++attempt) {
        if (t == 0) s_cnt = 0;
        __syncthreads();
        float thresh = vmax - W;
        #pragma unroll 8
        for (int it = 0; it < 32; ++it) {
            int vi = t + it * 512;              // < 16384
            float4a v = p4[vi];
            #pragma unroll
            for (int e = 0; e < 4; ++e) {
                float f = v[e];
                if (f >= thresh) {
                    int pos = atomicAdd(&s_cnt, 1);
                    if (pos < CAPL) { lv[pos] = f; li[pos] = vi * 4 + e; }
                }
            }
        }
        __syncthreads();
        cnt = s_cnt;
        if (cnt >= NH && cnt <= CAPL) break;
        W = (cnt > CAPL) ? W * 0.5f : W * 2.0f;
        __syncthreads();
    }
    if (cnt > CAPL) cnt = CAPL;   // pathological safety

    // ---- stage 2: fine prune (always) ----
    if (t < 128) hist[t] = 0;
    __syncthreads();
    float lo = vmax - W;
    float scale = 128.0f / W;
    for (int c = t; c < cnt; c += 512) {
        int b = (int)((lv[c] - lo) * scale);
        b = b < 0 ? 0 : (b > 127 ? 127 : b);
        atomicAdd(&hist[b], 1u);
    }
    __syncthreads();
    if (t == 0) {
        unsigned cum = 0; int b = 127;
        for (; b > 0; --b) { cum += hist[b]; if (cum >= NH) break; }
        int mb = (int)(0.25f * scale) + 1;     // 0.25 logit-unit safety margin
        b -= mb; if (b < 0) b = 0;
        long total = 0;
        for (int x = 127; x >= b; --x) total += hist[x];
        while (total > CAP && b < 127) { total -= hist[b]; ++b; }
        s_thr = b;
        s_cnt = 0;
    }
    __syncthreads();
    float thresh2 = lo + (float)s_thr * (W / 128.0f);
    for (int c = t; c < cnt; c += 512) {
        if (lv[c] >= thresh2) {
            int pos = atomicAdd(&s_cnt, 1);
            if (pos < CAP) cand[(size_t)row * CAP + pos] = li[c];
        }
    }
    __syncthreads();
    if (t == 0) ccnt[row] = (s_cnt < CAP) ? s_cnt : CAP;
}

// ---------------- Kernel D: fp64 re-rank + mixed-negative logits (R3-verbatim) ----
__global__ __launch_bounds__(256) void moco_finalize(const double* __restrict__ outq64,
                                                     const float* __restrict__ Qm,
                                                     const int* __restrict__ cand,
                                                     const int* __restrict__ ccnt,
                                                     const float* __restrict__ alpha,
                                                     const float* __restrict__ beta,
                                                     const int* __restrict__ i1a,
                                                     const int* __restrict__ i1b,
                                                     const int* __restrict__ i2,
                                                     float* __restrict__ out) {
    int row = blockIdx.x;
    __shared__ double oq[Dd];
    __shared__ double dval[CAP];
    __shared__ int didx[CAP];
    __shared__ int hard[NH];

    for (int i = threadIdx.x; i < Dd; i += 256) oq[i] = outq64[(size_t)row * Dd + i];
    __syncthreads();

    int n = ccnt[row]; if (n > CAP) n = CAP;
    for (int c = threadIdx.x; c < n; c += 256) {
        int idx = cand[(size_t)row * CAP + c];
        const float* qr = Qm + (size_t)idx * Dd;
        double dot = 0;
        #pragma unroll 4
        for (int i = 0; i < Dd; ++i) dot += oq[i] * (double)qr[i];
        dval[c] = dot / 0.07;
        didx[c] = idx;
    }
    __syncthreads();

    // exact rank (ties -> lower index first, matching lax.top_k)
    for (int c = threadIdx.x; c < n; c += 256) {
        double v = dval[c]; int id = didx[c];
        int r = 0;
        for (int j = 0; j < n; ++j) {
            double vj = dval[j];
            r += (vj > v) || (vj == v && didx[j] < id);
        }
        if (r < NH) hard[r] = id;
    }
    __syncthreads();

    int t = threadIdx.x;
    if (t < S1n) {
        double a = (double)alpha[(size_t)row * S1n + t];
        int g1 = hard[i1a[(size_t)row * S1n + t]];
        int g2 = hard[i1b[(size_t)row * S1n + t]];
        const float* q1 = Qm + (size_t)g1 * Dd;
        const float* q2 = Qm + (size_t)g2 * Dd;
        double nn = 0, qd = 0;
        #pragma unroll 4
        for (int i = 0; i < Dd; ++i) {
            double m = a * (double)q1[i] + (1.0 - a) * (double)q2[i];
            nn += m * m; qd += oq[i] * m;
        }
        double logit = qd / fmax(sqrt(nn), 1e-12) / 0.07;
        out[(size_t)row * ROWLEN + 1 + Kq + t] = (float)logit;
    } else if (t < S1n + S2n) {
        int s = t - S1n;
        double bb = (double)beta[(size_t)row * S2n + s] * 0.5;
        int g = hard[i2[(size_t)row * S2n + s]];
        const float* qg = Qm + (size_t)g * Dd;
        double nn = 0, qd = 0;
        #pragma unroll 4
        for (int i = 0; i < Dd; ++i) {
            double m = bb * oq[i] + (1.0 - bb) * (double)qg[i];
            nn += m * m; qd += oq[i] * m;
        }
        double logit = qd / fmax(sqrt(nn), 1e-12) / 0.07;
        out[(size_t)row * ROWLEN + 1 + Kq + S1n + s] = (float)logit;
    }
}

extern "C" void kernel_launch(void* const* d_in, const int* in_sizes, int n_in,
                              void* d_out, int out_size, void* d_ws, size_t ws_size,
                              hipStream_t stream) {
    const float* q     = (const float*)d_in[0];
    const float* k     = (const float*)d_in[1];
    const float* Wq    = (const float*)d_in[2];
    const float* Wk    = (const float*)d_in[3];
    const float* queue = (const float*)d_in[4];
    const float* alpha = (const float*)d_in[5];
    const float* beta  = (const float*)d_in[6];
    const int*   i1a   = (const int*)d_in[7];
    const int*   i1b   = (const int*)d_in[8];
    const int*   i2    = (const int*)d_in[9];
    float* out = (float*)d_out;

    // workspace layout (total 4.52 MB, same footprint as before):
    //   partq (f64, 2 MB) + partk (f32, 1 MB): dead after a2
    //   cand (2 MB) aliases partq, born in topcand
    //   wknew (1 MB): dead after a1; rmaxpart (512 KB) aliases it, born in gemmB
    char* ws = (char*)d_ws;
    double* partq  = (double*)(ws);                        // 2,097,152
    float*  partk  = (float*)(ws + 2097152);               // 1,048,576
    int*    cand   = (int*)(ws);                           // alias partq
    double* outq64 = (double*)(ws + 3145728);              // 262,144
    unsigned short* outq16 = (unsigned short*)(ws + 3145728 + 262144); // 65,536
    int*    ccnt   = (int*)(ws + 3145728 + 262144 + 65536);            // 1,024
    float* wknew   = (float*)(ws + 3145728 + 262144 + 65536 + 2048);   // 1,048,576
    unsigned* rmaxpart = (unsigned*)wknew;                  // alias, 512*256*4 = 524,288

    moco_a0<<<dim3(256), 256, 0, stream>>>(Wq, Wk, wknew);
    moco_a1<<<dim3(NCHUNK, 128), 256, 0, stream>>>(q, k, Wq, wknew, partq, partk);
    moco_a2<<<dim3(Bsz), 128, 0, stream>>>(partq, partk, outq64, outq16, out);
    moco_gemmB<<<dim3(GBLK), 256, 0, stream>>>(outq16, queue, rmaxpart, out);
    moco_topcand<<<dim3(Bsz), 512, 0, stream>>>(out, rmaxpart, cand, ccnt);
    moco_finalize<<<dim3(Bsz), 256, 0, stream>>>(outq64, queue, cand, ccnt,
                                                 alpha, beta, i1a, i1b, i2, out);
}